// Round 2
// baseline (681.634 us; speedup 1.0000x reference)
//
#include <hip/hip_runtime.h>

#define ROWS_PER_BLOCK 8
#define TPB 256
#define ROW_OUT 1225
#define TILE_OUT (ROWS_PER_BLOCK * ROW_OUT)   // 9800 floats = 39200 B, %16 == 0

// Triple index tables for N=5, K=3, i<=j<=k (35 entries)
__constant__ unsigned char c_I3[35] = {
    0,0,0,0,0,0,0,0,0,0,0,0,0,0,0,
    1,1,1,1,1,1,1,1,1,1,
    2,2,2,2,2,2,
    3,3,3,
    4};
__constant__ unsigned char c_J3[35] = {
    0,0,0,0,0,1,1,1,1,2,2,2,3,3,4,
    1,1,1,1,2,2,2,3,3,4,
    2,2,2,3,3,4,
    3,3,4,
    4};
__constant__ unsigned char c_K3[35] = {
    0,1,2,3,4,1,2,3,4,2,3,4,3,4,4,
    1,2,3,4,2,3,4,3,4,4,
    2,3,4,3,4,4,
    3,4,4,
    4};

__global__ __launch_bounds__(TPB) void bihom_k3_kernel(
    const float* __restrict__ z_re,
    const float* __restrict__ z_im,
    float* __restrict__ out,
    int B)
{
    __shared__ float  s_zre[ROWS_PER_BLOCK * 5];
    __shared__ float  s_zim[ROWS_PER_BLOCK * 5];
    __shared__ float2 s_zz[ROWS_PER_BLOCK * 35];
    __shared__ unsigned int s_pairs[630];               // p | q<<8
    __shared__ __align__(16) float s_out[TILE_OUT];     // staged output tile

    const int tid = threadIdx.x;
    const int row_base = blockIdx.x * ROWS_PER_BLOCK;
    const int rows = min(ROWS_PER_BLOCK, B - row_base);

    // --- stage z for this block's rows ---
    for (int idx = tid; idx < rows * 5; idx += TPB) {
        s_zre[idx] = z_re[row_base * 5 + idx];
        s_zim[idx] = z_im[row_base * 5 + idx];
    }

    // --- build packed pair table (630 pairs p<=q of 35) ---
    for (int t = tid; t < 630; t += TPB) {
        // offset(p) = p*(71-p)/2 ; (71-2p)^2 = 5041-8*offset(p) exact at boundaries
        float s = sqrtf((float)(5041 - 8 * t));
        int p = (int)((71.0f - s) * 0.5f);
        int q = p + (t - p * (71 - p) / 2);
        s_pairs[t] = (unsigned)p | ((unsigned)q << 8);
    }
    __syncthreads();

    // --- compute the 35 complex triple products per row ---
    for (int idx = tid; idx < rows * 35; idx += TPB) {
        int r = idx / 35;
        int m = idx - r * 35;
        int i = c_I3[m], j = c_J3[m], k = c_K3[m];
        float ar = s_zre[r * 5 + i], ai = s_zim[r * 5 + i];
        float br = s_zre[r * 5 + j], bi = s_zim[r * 5 + j];
        float cr = s_zre[r * 5 + k], ci = s_zim[r * 5 + k];
        // (a*b) left-assoc, then *c  (matches jnp elementwise complex mul order)
        float tr = ar * br - ai * bi;
        float ti = ar * bi + ai * br;
        float zr = tr * cr - ti * ci;
        float zi = tr * ci + ti * cr;
        s_zz[idx] = make_float2(zr, zi);
    }
    __syncthreads();

    // --- pair loop writes BOTH results into the staged LDS tile ---
    // re -> s_out[r*1225 + u]; im -> s_out[r*1225 + 630 + (u-p-1)] (strict pairs)
    const int total = rows * 630;
    for (int idx = tid; idx < total; idx += TPB) {
        int r = idx / 630;            // magic-mul
        int u = idx - r * 630;
        unsigned pk = s_pairs[u];
        int p = (int)(pk & 255u);
        int q = (int)(pk >> 8);
        float2 a = s_zz[r * 35 + p];
        float2 b = s_zz[r * 35 + q];
        // zz_p * conj(zz_q): re = ar*br + ai*bi ; im = ai*br - ar*bi
        float re = a.x * b.x + a.y * b.y;
        float im = a.y * b.x - a.x * b.y;
        int ro = r * ROW_OUT;
        s_out[ro + u] = re;
        if (p != q)
            s_out[ro + 630 + (u - p - 1)] = im;
    }
    __syncthreads();

    // --- dense, aligned float4 writeout: one contiguous 39200 B region/block ---
    if (rows == ROWS_PER_BLOCK) {
        const float4* src = (const float4*)s_out;
        float4* dst = (float4*)out + (size_t)blockIdx.x * (TILE_OUT / 4);
        #pragma unroll 2
        for (int i = tid; i < TILE_OUT / 4; i += TPB)
            dst[i] = src[i];
    } else {
        // tail block (B not multiple of 8): scalar fallback, still contiguous
        float* dst = out + (size_t)blockIdx.x * TILE_OUT;
        const int tf = rows * ROW_OUT;
        for (int i = tid; i < tf; i += TPB)
            dst[i] = s_out[i];
    }
}

extern "C" void kernel_launch(void* const* d_in, const int* in_sizes, int n_in,
                              void* d_out, int out_size, void* d_ws, size_t ws_size,
                              hipStream_t stream)
{
    const float* z_re = (const float*)d_in[0];
    const float* z_im = (const float*)d_in[1];
    float* out = (float*)d_out;
    const int B = in_sizes[0] / 5;
    const int blocks = (B + ROWS_PER_BLOCK - 1) / ROWS_PER_BLOCK;
    bihom_k3_kernel<<<blocks, TPB, 0, stream>>>(z_re, z_im, out, B);
}

// Round 4
// 632.070 us; speedup vs baseline: 1.0784x; 1.0784x over previous
//
#include <hip/hip_runtime.h>

#define ROWS_PER_BLOCK 8
#define TPB 256
#define ROW_OUT 1225
#define TILE_OUT (ROWS_PER_BLOCK * ROW_OUT)   // 9800 floats = 39200 B
#define TILE_V4  (TILE_OUT / 4)               // 2450 float4 per block

// Triple index tables for N=5, K=3, i<=j<=k (35 entries)
__constant__ unsigned char c_I3[35] = {
    0,0,0,0,0,0,0,0,0,0,0,0,0,0,0,
    1,1,1,1,1,1,1,1,1,1,
    2,2,2,2,2,2,
    3,3,3,
    4};
__constant__ unsigned char c_J3[35] = {
    0,0,0,0,0,1,1,1,1,2,2,2,3,3,4,
    1,1,1,1,2,2,2,3,3,4,
    2,2,2,3,3,4,
    3,3,4,
    4};
__constant__ unsigned char c_K3[35] = {
    0,1,2,3,4,1,2,3,4,2,3,4,3,4,4,
    1,2,3,4,2,3,4,3,4,4,
    2,3,4,3,4,4,
    3,4,4,
    4};

__global__ __launch_bounds__(TPB) void bihom_k3_kernel(
    const float* __restrict__ z_re,
    const float* __restrict__ z_im,
    float* __restrict__ out,
    int B)
{
    __shared__ float  s_zre[ROWS_PER_BLOCK * 5];
    __shared__ float  s_zim[ROWS_PER_BLOCK * 5];
    __shared__ float2 s_zz[ROWS_PER_BLOCK * 35];
    __shared__ unsigned int s_tab[ROW_OUT];   // p | q<<8 | flag<<16, per output col

    const int tid = threadIdx.x;
    const int row_base = blockIdx.x * ROWS_PER_BLOCK;
    const int rows = min(ROWS_PER_BLOCK, B - row_base);

    // --- stage z for this block's rows ---
    for (int idx = tid; idx < rows * 5; idx += TPB) {
        s_zre[idx] = z_re[row_base * 5 + idx];
        s_zim[idx] = z_im[row_base * 5 + idx];
    }

    // --- build packed output-index table (R0-proven decode) ---
    for (int t = tid; t < ROW_OUT; t += TPB) {
        int p, q;
        unsigned flag;
        if (t < 630) {
            // pairs p<=q of 35: offset(p) = p*(71-p)/2
            flag = 0u;
            int u = t;
            float s = sqrtf((float)(5041 - 8 * u));   // (71-2p)^2 at boundaries (exact)
            p = (int)((71.0f - s) * 0.5f);
            q = p + (u - p * (71 - p) / 2);
        } else {
            // strict pairs p<q: offset(p) = p*(69-p)/2
            flag = 1u;
            int u = t - 630;
            float s = sqrtf((float)(4761 - 8 * u));   // (69-2p)^2 at boundaries (exact)
            p = (int)((69.0f - s) * 0.5f);
            q = p + 1 + (u - p * (69 - p) / 2);
        }
        s_tab[t] = (unsigned)p | ((unsigned)q << 8) | (flag << 16);
    }
    __syncthreads();

    // --- compute the 35 complex triple products per row ---
    for (int idx = tid; idx < rows * 35; idx += TPB) {
        int r = idx / 35;
        int m = idx - r * 35;
        int i = c_I3[m], j = c_J3[m], k = c_K3[m];
        float ar = s_zre[r * 5 + i], ai = s_zim[r * 5 + i];
        float br = s_zre[r * 5 + j], bi = s_zim[r * 5 + j];
        float cr = s_zre[r * 5 + k], ci = s_zim[r * 5 + k];
        // (a*b) left-assoc, then *c  (matches jnp elementwise complex mul order)
        float tr = ar * br - ai * bi;
        float ti = ar * bi + ai * br;
        float zr = tr * cr - ti * ci;
        float zi = tr * ci + ti * cr;
        s_zz[idx] = make_float2(zr, zi);
    }
    __syncthreads();

    // one output element: reads table+zz, leaves result in vdst, steps (t,r)
#define ELEM(vdst)                                                \
    {                                                             \
        unsigned pk = s_tab[t];                                   \
        int p = (int)(pk & 255u);                                 \
        int q = (int)((pk >> 8) & 255u);                          \
        float2 a = s_zz[r * 35 + p];                              \
        float2 b = s_zz[r * 35 + q];                              \
        float re = a.x * b.x + a.y * b.y;                         \
        float im = a.y * b.x - a.x * b.y;                         \
        vdst = (pk & 0x10000u) ? im : re;                         \
        if (++t == ROW_OUT) { t = 0; ++r; }                       \
    }

    if (rows == ROWS_PER_BLOCK) {
        // --- fast path: one float4 store per thread-iteration, dense tile ---
        float4* dst = (float4*)out + (size_t)blockIdx.x * TILE_V4;
        for (int i = tid; i < TILE_V4; i += TPB) {
            int o = i * 4;                // offset within 9800-float tile
            int r = o / ROW_OUT;          // magic-mul div
            int t = o - r * ROW_OUT;
            float v0, v1, v2, v3;
            ELEM(v0) ELEM(v1) ELEM(v2) ELEM(v3)
            dst[i] = make_float4(v0, v1, v2, v3);
        }
    } else {
        // --- tail block: scalar stores, same dense layout ---
        float* dst = out + (size_t)blockIdx.x * TILE_OUT;
        const int total = rows * ROW_OUT;
        for (int idx = tid; idx < total; idx += TPB) {
            int r = idx / ROW_OUT;
            int t = idx - r * ROW_OUT;
            float v;
            ELEM(v)
            dst[idx] = v;
        }
    }
#undef ELEM
}

extern "C" void kernel_launch(void* const* d_in, const int* in_sizes, int n_in,
                              void* d_out, int out_size, void* d_ws, size_t ws_size,
                              hipStream_t stream)
{
    const float* z_re = (const float*)d_in[0];
    const float* z_im = (const float*)d_in[1];
    float* out = (float*)d_out;
    const int B = in_sizes[0] / 5;
    const int blocks = (B + ROWS_PER_BLOCK - 1) / ROWS_PER_BLOCK;
    bihom_k3_kernel<<<blocks, TPB, 0, stream>>>(z_re, z_im, out, B);
}